// Round 10
// baseline (462.369 us; speedup 1.0000x reference)
//
#include <hip/hip_runtime.h>
#include <hip/hip_fp16.h>

#define NPTS 500000
#define RPLANE 128
#define FDIM 32
#define PLSZ (RPLANE * RPLANE * FDIM)
#define NTILES 15625          // 500000 / 32
#define NWAVES 2048           // 256 blocks x 8 waves

typedef __bf16 bfx8 __attribute__((ext_vector_type(8)));
typedef float f32x4 __attribute__((ext_vector_type(4)));

__device__ __forceinline__ unsigned short f2bf(float f) {
    unsigned int u = __builtin_bit_cast(unsigned int, f);
    unsigned int r = (u + 0x7FFFu + ((u >> 16) & 1u)) >> 16;
    return (unsigned short)r;
}

__device__ __forceinline__ unsigned pk2(float a, float b) {
    return (unsigned)f2bf(a) | ((unsigned)f2bf(b) << 16);
}

// packed f32x2 -> bf16x2 (RNE), single instruction (used in gather only)
__device__ __forceinline__ unsigned cvtpk(float a, float b) {
    unsigned r;
    asm("v_cvt_pk_bf16_f32 %0, %1, %2" : "=v"(r) : "v"(a), "v"(b));
    return r;
}

__device__ __forceinline__ __half2 u2h(unsigned u) {
    return __builtin_bit_cast(__half2, u);
}

__device__ __forceinline__ bfx8 asfrag(uint4 v) {
    return __builtin_bit_cast(bfx8, v);
}

// D->act-frag conversion via ds_bpermute (mlp6-proven path).
__device__ __forceinline__ uint4 convD(unsigned e0, unsigned e1, unsigned o0,
                                       unsigned o1, int a0, int a1, bool sel) {
    uint4 W;
    int x, y;
    x = __builtin_amdgcn_ds_bpermute(a0, (int)e0);
    y = __builtin_amdgcn_ds_bpermute(a0, (int)o0);
    W.x = (unsigned)(sel ? y : x);
    x = __builtin_amdgcn_ds_bpermute(a0, (int)e1);
    y = __builtin_amdgcn_ds_bpermute(a0, (int)o1);
    W.y = (unsigned)(sel ? y : x);
    x = __builtin_amdgcn_ds_bpermute(a1, (int)e0);
    y = __builtin_amdgcn_ds_bpermute(a1, (int)o0);
    W.z = (unsigned)(sel ? y : x);
    x = __builtin_amdgcn_ds_bpermute(a1, (int)e1);
    y = __builtin_amdgcn_ds_bpermute(a1, (int)o1);
    W.w = (unsigned)(sel ? y : x);
    return W;
}

// Repack weight mats to bf16 MFMA frags (natural columns) + planes to fp16
// (vectorized float2->half2).
// Frag block b = ct*(K/32)+ks, lane l, elem j: W[k=ks*32+(l>>4)*8+j][col=ct*16+(l&15)].
__global__ void prep2(const float* __restrict__ wenc, const float* __restrict__ w1,
                      const float* __restrict__ w2, const float* __restrict__ spf,
                      const float* __restrict__ tpf,
                      unsigned short* __restrict__ wf, __half* __restrict__ ph) {
    const int WTOT = 86016;
    const int PHALF = 3 * PLSZ;           // PTOT/2 pairs
    const int total = WTOT + PHALF;
    for (int i = blockIdx.x * blockDim.x + threadIdx.x; i < total;
         i += gridDim.x * blockDim.x) {
        if (i < WTOT) {
            const float* W;
            unsigned short* dst;
            int K, Ncols, idx;
            if (i < 8192)       { W = wenc; K = 32;  Ncols = 256; idx = i;         dst = wf; }
            else if (i < 73728) { W = w1;   K = 256; Ncols = 256; idx = i - 8192;  dst = wf + 8192; }
            else                { W = w2;   K = 256; Ncols = 48;  idx = i - 73728; dst = wf + 73728; }
            int j = idx & 7;
            int l = (idx >> 3) & 63;
            int b = idx >> 9;
            int KS = K >> 5;
            int ct = b / KS;
            int ks = b - ct * KS;
            int k = ks * 32 + ((l >> 4) << 3) + j;
            int col = ct * 16 + (l & 15);
            dst[idx] = f2bf(W[(size_t)k * Ncols + col]);
        } else {
            int j2 = (i - WTOT) * 2;
            const float* src = (j2 < 3 * PLSZ) ? spf + j2 : tpf + (j2 - 3 * PLSZ);
            float2 v = *(const float2*)src;
            *(__half2*)(ph + j2) = __floats2half2_rn(v.x, v.y);
        }
    }
}

// Gather: 2 threads/point, 3 planes each, combine via shfl_xor(1).
// h==0 lane also does passthrough copies and writes the A-frag.
__global__ __launch_bounds__(256) void gather2(
    const float* __restrict__ rays, const float* __restrict__ tme,
    const float* __restrict__ rot, const float* __restrict__ h_e,
    const __half* __restrict__ ph, float* __restrict__ out) {
    int t = blockIdx.x * blockDim.x + threadIdx.x;
    int p = t >> 1, h = t & 1;
    if (p >= NPTS) return;

    float3 r3 = *(const float3*)(rays + 3 * p);
    const float inv = 0.625f;
    float xn = fminf(fmaxf(r3.x * inv, -1.f), 1.f) * 0.5f + 0.5f;
    float yn = fminf(fmaxf(r3.y * inv, -1.f), 1.f) * 0.5f + 0.5f;
    float zn = fminf(fmaxf(r3.z * inv, -1.f), 1.f) * 0.5f + 0.5f;
    float tt = fminf(fmaxf(tme[p], 0.f), 1.f);
    float c4[4] = {xn, yn, zn, tt};
    int i0[4];
    float fr[4];
#pragma unroll
    for (int cc = 0; cc < 4; ++cc) {
        float x = c4[cc] * 127.0f;
        float xf = fminf(floorf(x), 126.0f);
        i0[cc] = (int)xf;
        fr[cc] = x - xf;
    }
    // h=0: planes 0(x,y) 1(x,z) 2(y,z); h=1: planes 3(x,t) 4(y,t) 5(z,t)
    __half2 g2[16];
#pragma unroll
    for (int q = 0; q < 3; ++q) {
        int iu = h ? q : ((q == 2) ? 1 : 0);
        int iv = h ? 3 : ((q == 0) ? 1 : 2);
        int pl = 3 * h + q;
        int x0 = i0[iu], y0 = i0[iv];
        float fx = fr[iu], fy = fr[iv];
        const __half* base = ph + (size_t)pl * PLSZ + ((y0 * RPLANE + x0) << 5);
        const uint4* b00 = (const uint4*)base;
        const uint4* b01 = (const uint4*)(base + FDIM);
        const uint4* b10 = (const uint4*)(base + RPLANE * FDIM);
        const uint4* b11 = (const uint4*)(base + RPLANE * FDIM + FDIM);
        __half2 wa = __float2half2_rn((1.f - fx) * (1.f - fy));
        __half2 wb = __float2half2_rn(fx * (1.f - fy));
        __half2 wc = __float2half2_rn((1.f - fx) * fy);
        __half2 wd = __float2half2_rn(fx * fy);
#pragma unroll
        for (int qq = 0; qq < 4; ++qq) {
            uint4 A = b00[qq], B = b01[qq], C = b10[qq], D = b11[qq];
            unsigned ua[4] = {A.x, A.y, A.z, A.w};
            unsigned ub[4] = {B.x, B.y, B.z, B.w};
            unsigned uccr[4] = {C.x, C.y, C.z, C.w};
            unsigned ud[4] = {D.x, D.y, D.z, D.w};
#pragma unroll
            for (int j = 0; j < 4; ++j) {
                __half2 r = __hmul2(u2h(ua[j]), wa);
                r = __hfma2(u2h(ub[j]), wb, r);
                r = __hfma2(u2h(uccr[j]), wc, r);
                r = __hfma2(u2h(ud[j]), wd, r);
                int i = qq * 4 + j;
                g2[i] = (q == 0) ? r : __hmul2(g2[i], r);
            }
        }
    }
    // combine the two half-products
#pragma unroll
    for (int i = 0; i < 16; ++i) {
        int o = __shfl_xor(__builtin_bit_cast(int, g2[i]), 1);
        g2[i] = __hmul2(g2[i], __builtin_bit_cast(__half2, o));
    }
    if (h == 0) {
        // passthrough
        out[3 * p + 0] = r3.x;
        out[3 * p + 1] = r3.y;
        out[3 * p + 2] = r3.z;
        float4 r4 = *(const float4*)(rot + 4 * p);
        *(float4*)(out + 3 * NPTS + 4 * p) = r4;
        out[7 * NPTS + p] = h_e[2 * p];
        // write A-frag order: ftile f, lane gg*16+c holds feats 8gg..8gg+7 of point c
        int f = p >> 4, c = p & 15;
        char* fb = (char*)out + (size_t)NPTS * 32 + (size_t)f * 3072;
#pragma unroll
        for (int gg = 0; gg < 4; ++gg) {
            float2 v0 = __half22float2(g2[4 * gg + 0]);
            float2 v1 = __half22float2(g2[4 * gg + 1]);
            float2 v2 = __half22float2(g2[4 * gg + 2]);
            float2 v3 = __half22float2(g2[4 * gg + 3]);
            uint4 av;
            av.x = cvtpk(v0.x, v0.y);
            av.y = cvtpk(v1.x, v1.y);
            av.z = cvtpk(v2.x, v2.y);
            av.w = cvtpk(v3.x, v3.y);
            *(uint4*)(fb + (gg * 16 + c) * 16) = av;
        }
    }
}

// Compute-phase kernel: mlp6 structure (bpermute convD, manual pk2) +
// latency prefetching: shs hoisted to tile start, layer-2 LDS dbuf,
// layer-1 weight dbuf, next-tile act1 prefetch.
__global__ __launch_bounds__(512, 1) void mlp9(
    const float* __restrict__ shs, const unsigned short* __restrict__ wf,
    const float* __restrict__ benc, const float* __restrict__ b1v,
    const float* __restrict__ b2v, float* __restrict__ out) {
    __shared__ unsigned short wlds[77824];   // w1 frags [0,65536) + w2 frags [65536,77824)
    const int tid = threadIdx.x;
    const int wid = tid >> 6;
    const int lane = tid & 63;
#pragma unroll
    for (int i = tid * 8; i < 77824; i += 512 * 8)
        *(uint4*)&wlds[i] = *(const uint4*)(wf + 8192 + i);
    __syncthreads();

    const int g = lane >> 4;
    const int c = lane & 15;
    const int a0 = 4 * (32 * (g & 1) + c);
    const int a1 = a0 + 64;
    const bool sel = (g >> 1) != 0;
    const char* fb = (const char*)out + (size_t)NPTS * 32;
    const int w = blockIdx.x * 8 + wid;

    // prologue: act1 for first tile (tile = w, always < NTILES)
    bfx8 act1[2];
    act1[0] = asfrag(*(const uint4*)(fb + (size_t)(2 * w + 0) * 3072 + lane * 16));
    act1[1] = asfrag(*(const uint4*)(fb + (size_t)(2 * w + 1) * 3072 + lane * 16));

    for (int it = 0; it < 8; ++it) {
        int tile = w + NWAVES * it;
        if (tile >= NTILES) break;
        const int p0 = tile * 32;

        // ---- prefetch shs for this tile (consumed in layer 3) ----
        float sh[2][3][4];
#pragma unroll
        for (int pt = 0; pt < 2; ++pt)
#pragma unroll
            for (int ct3 = 0; ct3 < 3; ++ct3)
#pragma unroll
                for (int r = 0; r < 4; ++r)
                    sh[pt][ct3][r] =
                        shs[(size_t)(p0 + pt * 16 + 4 * g + r) * 48 + 16 * ct3 + c];

        // ---- layer 1: wenc frags from global (dbuf); convD -> act2 ----
        uint4 act2[2][8];
        {
            uint4 wA = *(const uint4*)(wf + (size_t)0 * 512 + lane * 8);
            uint4 wB;
            unsigned stE[2][2];
#pragma unroll
            for (int ct = 0; ct < 16; ++ct) {
                uint4 cur = (ct & 1) ? wB : wA;
                if (ct < 15) {
                    uint4 nx = *(const uint4*)(wf + (size_t)(ct + 1) * 512 + lane * 8);
                    if (ct & 1) wA = nx; else wB = nx;
                }
                float4 b4 = *(const float4*)(benc + 16 * ct + 4 * g);
                float bb[4] = {b4.x, b4.y, b4.z, b4.w};
#pragma unroll
                for (int pt = 0; pt < 2; ++pt) {
                    f32x4 z = {0.f, 0.f, 0.f, 0.f};
                    f32x4 d = __builtin_amdgcn_mfma_f32_16x16x32_bf16(asfrag(cur), act1[pt], z, 0, 0, 0);
                    float v0 = fmaxf(d[0] + bb[0], 0.f);
                    float v1 = fmaxf(d[1] + bb[1], 0.f);
                    float v2 = fmaxf(d[2] + bb[2], 0.f);
                    float v3 = fmaxf(d[3] + bb[3], 0.f);
                    unsigned Q0 = pk2(v0, v1), Q1 = pk2(v2, v3);
                    if ((ct & 1) == 0) {
                        stE[pt][0] = Q0; stE[pt][1] = Q1;
                    } else {
                        act2[pt][ct >> 1] = convD(stE[pt][0], stE[pt][1], Q0, Q1, a0, a1, sel);
                    }
                }
            }
        }

        // ---- prefetch next tile's act1 (covered by layers 2-3) ----
        uint4 a1n0, a1n1;
        {
            int tile2 = tile + NWAVES;
            int t2 = (tile2 < NTILES) ? tile2 : tile;
            a1n0 = *(const uint4*)(fb + (size_t)(2 * t2 + 0) * 3072 + lane * 16);
            a1n1 = *(const uint4*)(fb + (size_t)(2 * t2 + 1) * 3072 + lane * 16);
        }

        // ---- layer 2: w1 frags from LDS with double-buffer; convD -> act3 ----
        uint4 act3[2][8];
        {
            uint4 wv0[8], wv1[8];
#pragma unroll
            for (int ks = 0; ks < 8; ++ks)
                wv0[ks] = *(const uint4*)&wlds[ks * 512 + lane * 8];
            unsigned stE[2][2];
#pragma unroll
            for (int ct = 0; ct < 16; ++ct) {
                if (ct < 15) {
#pragma unroll
                    for (int ks = 0; ks < 8; ++ks) {
                        uint4 nx = *(const uint4*)&wlds[((ct + 1) * 8 + ks) * 512 + lane * 8];
                        if (ct & 1) wv0[ks] = nx; else wv1[ks] = nx;
                    }
                }
                float4 b4 = *(const float4*)(b1v + 16 * ct + 4 * g);
                float bb[4] = {b4.x, b4.y, b4.z, b4.w};
#pragma unroll
                for (int pt = 0; pt < 2; ++pt) {
                    f32x4 acc = {0.f, 0.f, 0.f, 0.f};
#pragma unroll
                    for (int ks = 0; ks < 8; ++ks) {
                        uint4 wk = (ct & 1) ? wv1[ks] : wv0[ks];
                        acc = __builtin_amdgcn_mfma_f32_16x16x32_bf16(asfrag(wk), asfrag(act2[pt][ks]), acc, 0, 0, 0);
                    }
                    float v0 = fmaxf(acc[0] + bb[0], 0.f);
                    float v1 = fmaxf(acc[1] + bb[1], 0.f);
                    float v2 = fmaxf(acc[2] + bb[2], 0.f);
                    float v3 = fmaxf(acc[3] + bb[3], 0.f);
                    unsigned Q0 = pk2(v0, v1), Q1 = pk2(v2, v3);
                    if ((ct & 1) == 0) {
                        stE[pt][0] = Q0; stE[pt][1] = Q1;
                    } else {
                        act3[pt][ct >> 1] = convD(stE[pt][0], stE[pt][1], Q0, Q1, a0, a1, sel);
                    }
                }
            }
        }

        // ---- layer 3: w2 frags from LDS; + b2 + prefetched shs -> out ----
        {
#pragma unroll
            for (int ct = 0; ct < 3; ++ct) {
                uint4 wl[8];
#pragma unroll
                for (int ks = 0; ks < 8; ++ks)
                    wl[ks] = *(const uint4*)&wlds[65536 + (ct * 8 + ks) * 512 + lane * 8];
                float bias = b2v[16 * ct + c];
#pragma unroll
                for (int pt = 0; pt < 2; ++pt) {
                    f32x4 acc = {0.f, 0.f, 0.f, 0.f};
#pragma unroll
                    for (int ks = 0; ks < 8; ++ks)
                        acc = __builtin_amdgcn_mfma_f32_16x16x32_bf16(asfrag(act3[pt][ks]), asfrag(wl[ks]), acc, 0, 0, 0);
#pragma unroll
                    for (int r = 0; r < 4; ++r) {
                        int p = p0 + pt * 16 + 4 * g + r;
                        size_t idx = (size_t)p * 48 + 16 * ct + c;
                        out[(size_t)NPTS * 8 + idx] = sh[pt][ct][r] + acc[r] + bias;
                    }
                }
            }
        }

        act1[0] = asfrag(a1n0);
        act1[1] = asfrag(a1n1);
    }
}

extern "C" void kernel_launch(void* const* d_in, const int* in_sizes, int n_in,
                              void* d_out, int out_size, void* d_ws, size_t ws_size,
                              hipStream_t stream) {
    const float* rays = (const float*)d_in[0];
    const float* rot  = (const float*)d_in[1];
    const float* shs  = (const float*)d_in[3];
    const float* tme  = (const float*)d_in[5];
    const float* h_e  = (const float*)d_in[6];
    const float* spf  = (const float*)d_in[7];
    const float* tpf  = (const float*)d_in[8];
    const float* wenc = (const float*)d_in[9];
    const float* benc = (const float*)d_in[10];
    const float* w1   = (const float*)d_in[11];
    const float* b1v  = (const float*)d_in[12];
    const float* w2   = (const float*)d_in[13];
    const float* b2v  = (const float*)d_in[14];
    float* out = (float*)d_out;
    unsigned short* wf = (unsigned short*)d_ws;    // 86016 shorts of weight frags
    __half* ph = (__half*)(wf + 86016);            // 6*PLSZ fp16 plane cache (~6.3 MB)

    prep2<<<2048, 256, 0, stream>>>(wenc, w1, w2, spf, tpf, wf, ph);
    gather2<<<(2 * NPTS + 255) / 256, 256, 0, stream>>>(rays, tme, rot, h_e, ph, out);
    mlp9<<<256, 512, 0, stream>>>(shs, wf, benc, b1v, b2v, out);
}